// Round 3
// baseline (597.458 us; speedup 1.0000x reference)
//
#include <hip/hip_runtime.h>
#include <stdint.h>

typedef __attribute__((ext_vector_type(8))) short short8;
typedef __attribute__((ext_vector_type(4))) float floatx4;
typedef unsigned short ushort_t;

__device__ __forceinline__ ushort_t f2bf(float f) {
    union { float f; unsigned int i; } v; v.f = f;
    unsigned int r = v.i + 0x7fffu + ((v.i >> 16) & 1u);  // RNE
    return (ushort_t)(r >> 16);
}

// B=8, N=1024 (rows R=8192), P=16, D=512 (GEMM K), E=8192 (P*D)

// ---------- W2 fp32 [512][8192] -> W2T bf16 [8192][512] ----------
__global__ __launch_bounds__(256) void k_prep(
    const float* __restrict__ W2, ushort_t* __restrict__ W2T)
{
    __shared__ float t[32][33];
    const int tid = threadIdx.x;
    const int tx = tid & 31, ty = tid >> 5;      // 32 x 8
    const int e0 = blockIdx.x * 32, k0 = blockIdx.y * 32;
#pragma unroll
    for (int i = 0; i < 4; ++i)
        t[ty + i * 8][tx] = W2[(size_t)(k0 + ty + i * 8) * 8192 + e0 + tx];
    __syncthreads();
#pragma unroll
    for (int i = 0; i < 4; ++i)
        W2T[(size_t)(e0 + ty + i * 8) * 512 + k0 + tx] = f2bf(t[tx][ty + i * 8]);
}

// ---------- h[r][d] = relu(xp[r][:16] @ W1[:, d] + b1[d]), bf16 out ----------
__global__ __launch_bounds__(256) void k1_hidden(
    const float* __restrict__ x, const float* __restrict__ W1,
    const float* __restrict__ b1, ushort_t* __restrict__ h)
{
    __shared__ float xs[16];
    const int r = blockIdx.x;
    const int tid = threadIdx.x;
    if (tid < 16) xs[tid] = x[r * 16 + tid];
    __syncthreads();
#pragma unroll
    for (int dd = 0; dd < 2; ++dd) {
        int d = tid + dd * 256;
        float s = b1[d];
#pragma unroll
        for (int p = 0; p < 16; ++p)
            s += xs[p] * W1[p * 512 + d];
        s = s > 0.f ? s : 0.f;
        h[(size_t)r * 512 + d] = f2bf(s);
    }
}

// ---------- pass A: GEMM -> exp column partial sums (register staging, round-0 proven) ----------
__global__ __launch_bounds__(256) void k2_sums(
    const ushort_t* __restrict__ h,     // [8192][512] bf16
    const ushort_t* __restrict__ W2T,   // [8192][512] bf16
    const float* __restrict__ b2,       // [8192]
    float* __restrict__ P)              // [64 row-blocks][8192] partial col sums
{
    __shared__ __align__(16) ushort_t As[128 * 32];
    __shared__ __align__(16) ushort_t Bs[128 * 32];
    __shared__ float csum[128];
    const int tid = threadIdx.x;
    const int lane = tid & 63;
    const int wave = tid >> 6;
    const int quad = lane >> 4;
    const int l16 = lane & 15;
    const int i0 = blockIdx.x * 128;
    const int e0 = blockIdx.y * 128;
    const int wr = (wave >> 1) * 64;
    const int wc = (wave & 1) * 64;

    if (tid < 128) csum[tid] = 0.f;

    floatx4 acc[4][4];
#pragma unroll
    for (int i = 0; i < 4; ++i)
#pragma unroll
        for (int j = 0; j < 4; ++j)
            acc[i][j] = (floatx4){0.f, 0.f, 0.f, 0.f};

    for (int k0 = 0; k0 < 512; k0 += 32) {
#pragma unroll
        for (int s = 0; s < 2; ++s) {
            int q = tid + s * 256;           // 16B chunk id
            int row = q >> 2;                // local row
            int c = q & 3;                   // chunk within row
            uint4 va = *reinterpret_cast<const uint4*>(&h[(size_t)(i0 + row) * 512 + k0 + c * 8]);
            uint4 vb = *reinterpret_cast<const uint4*>(&W2T[(size_t)(e0 + row) * 512 + k0 + c * 8]);
            *reinterpret_cast<uint4*>(&As[row * 32 + ((c ^ (row & 3)) << 3)]) = va;
            *reinterpret_cast<uint4*>(&Bs[row * 32 + ((c ^ (row & 3)) << 3)]) = vb;
        }
        __syncthreads();
        short8 af[4], bf[4];
#pragma unroll
        for (int i = 0; i < 4; ++i) {
            int m = wr + i * 16 + l16;
            af[i] = *reinterpret_cast<const short8*>(&As[m * 32 + ((quad ^ (m & 3)) << 3)]);
            int n = wc + i * 16 + l16;
            bf[i] = *reinterpret_cast<const short8*>(&Bs[n * 32 + ((quad ^ (n & 3)) << 3)]);
        }
#pragma unroll
        for (int i = 0; i < 4; ++i)
#pragma unroll
            for (int j = 0; j < 4; ++j)
                acc[i][j] = __builtin_amdgcn_mfma_f32_16x16x32_bf16(af[i], bf[j], acc[i][j], 0, 0, 0);
        __syncthreads();
    }

#pragma unroll
    for (int j = 0; j < 4; ++j) {
        int eg = e0 + wc + j * 16 + l16;
        float b2v = b2[eg];
        float csj = 0.f;
#pragma unroll
        for (int i = 0; i < 4; ++i)
#pragma unroll
            for (int r = 0; r < 4; ++r) {
                float v = acc[i][j][r] + b2v;
                v = v > 0.f ? v : 0.f;
                csj += __expf(v);
            }
        csj += __shfl_xor(csj, 16, 64);
        csj += __shfl_xor(csj, 32, 64);
        if (lane < 16) atomicAdd(&csum[wc + j * 16 + l16], csj);
    }
    __syncthreads();
    if (tid < 128) P[(size_t)blockIdx.x * 8192 + e0 + tid] = csum[tid];
}

// ---------- reduce 8 row-block partials per batch -> reciprocal denominators ----------
__global__ __launch_bounds__(256) void k_rdenom(const float* __restrict__ P,
                                                float* __restrict__ rden)
{
    int idx = blockIdx.x * 256 + threadIdx.x;   // b*8192 + e
    int b = idx >> 13;
    int e = idx & 8191;
    float s = 0.f;
#pragma unroll
    for (int j = 0; j < 8; ++j) s += P[(size_t)(b * 8 + j) * 8192 + e];
    rden[idx] = 1.0f / s;
}

// ---------- pass B: recompute GEMM with 1-d halo; each WAVE owns 32 rows x all 160 e-cols ----------
// 10 d-tiles per wave (t=0..9 -> d_global = d0-1+t); pooling fully in-register, no exchange.
__global__ __launch_bounds__(256) void k2_final(
    const ushort_t* __restrict__ h,
    const ushort_t* __restrict__ W2T,
    const float* __restrict__ b2,
    const float* __restrict__ x,        // xp [8192][16]
    const float* __restrict__ rden,     // [8][8192]
    float* __restrict__ out)            // [8192*16][512]
{
    __shared__ __align__(16) ushort_t As[128 * 32];
    __shared__ __align__(16) ushort_t Bs[160 * 32];
    __shared__ float xs[128 * 17];
    const int tid = threadIdx.x;
    const int lane = tid & 63;
    const int wave = tid >> 6;
    const int quad = lane >> 4;
    const int l16 = lane & 15;
    const int i0 = blockIdx.x * 128;
    const int d0 = blockIdx.y * 8;
    const int ebase = blockIdx.y * 128 - 16;  // e_global of e_local 0 (may be -16)
    const int wrow = wave * 32;               // wave's 32-row slice
    const int b = i0 >> 10;

#pragma unroll
    for (int s = 0; s < 8; ++s) {
        int q = tid + s * 256;
        xs[(q >> 4) * 17 + (q & 15)] = x[(size_t)(i0 + (q >> 4)) * 16 + (q & 15)];
    }

    floatx4 acc[2][10];
#pragma unroll
    for (int i = 0; i < 2; ++i)
#pragma unroll
        for (int t = 0; t < 10; ++t)
            acc[i][t] = (floatx4){0.f, 0.f, 0.f, 0.f};

    for (int k0 = 0; k0 < 512; k0 += 32) {
#pragma unroll
        for (int s = 0; s < 2; ++s) {
            int q = tid + s * 256;
            int row = q >> 2, c = q & 3;
            uint4 va = *reinterpret_cast<const uint4*>(&h[(size_t)(i0 + row) * 512 + k0 + c * 8]);
            *reinterpret_cast<uint4*>(&As[row * 32 + ((c ^ (row & 3)) << 3)]) = va;
        }
#pragma unroll
        for (int s = 0; s < 3; ++s) {
            int q = tid + s * 256;           // 640 chunks total
            if (q < 640) {
                int row = q >> 2, c = q & 3;
                int eg = ebase + row;
                eg = eg < 0 ? 0 : (eg > 8191 ? 8191 : eg);   // clamp; halo zeroed in epilogue
                uint4 vb = *reinterpret_cast<const uint4*>(&W2T[(size_t)eg * 512 + k0 + c * 8]);
                *reinterpret_cast<uint4*>(&Bs[row * 32 + ((c ^ (row & 3)) << 3)]) = vb;
            }
        }
        __syncthreads();
        short8 af[2], bf[10];
#pragma unroll
        for (int i = 0; i < 2; ++i) {
            int m = wrow + i * 16 + l16;
            af[i] = *reinterpret_cast<const short8*>(&As[m * 32 + ((quad ^ (m & 3)) << 3)]);
        }
#pragma unroll
        for (int t = 0; t < 10; ++t) {
            int n = t * 16 + l16;
            bf[t] = *reinterpret_cast<const short8*>(&Bs[n * 32 + ((quad ^ (n & 3)) << 3)]);
        }
#pragma unroll
        for (int i = 0; i < 2; ++i)
#pragma unroll
            for (int t = 0; t < 10; ++t)
                acc[i][t] = __builtin_amdgcn_mfma_f32_16x16x32_bf16(af[i], bf[t], acc[i][t], 0, 0, 0);
        __syncthreads();
    }

    // acc <- g = exp(relu(acc + b2)) * rden[e] * xp[row][p]   (halo out-of-range -> 0)
#pragma unroll
    for (int t = 0; t < 10; ++t) {
        int el = t * 16 + l16;
        int eg = ebase + el;
        int valid = (eg >= 0) & (eg < 8192);
        int egc = valid ? eg : 0;
        float b2v = b2[egc];
        float scale = valid ? rden[b * 8192 + egc] : 0.f;
#pragma unroll
        for (int i = 0; i < 2; ++i) {
            int rbase = wrow + i * 16 + quad * 4;
#pragma unroll
            for (int r = 0; r < 4; ++r) {
                float v = acc[i][t][r] + b2v;
                v = v > 0.f ? v : 0.f;
                acc[i][t][r] = __expf(v) * scale * xs[(rbase + r) * 17 + l16];
            }
        }
    }

    // in-register 3-tap pool over d; two float4 stores per (i,r)
    const float inv3 = 1.f / 3.f;
#pragma unroll
    for (int i = 0; i < 2; ++i) {
        int rbase = wrow + i * 16 + quad * 4;
#pragma unroll
        for (int r = 0; r < 4; ++r) {
            int row = rbase + r;
            float g0 = acc[i][0][r], g1 = acc[i][1][r], g2 = acc[i][2][r];
            float g3 = acc[i][3][r], g4 = acc[i][4][r], g5 = acc[i][5][r];
            float g6 = acc[i][6][r], g7 = acc[i][7][r], g8 = acc[i][8][r];
            float g9 = acc[i][9][r];
            float4 o1, o2;
            o1.x = (g0 + g1 + g2) * inv3;   // d0+0
            o1.y = (g1 + g2 + g3) * inv3;   // d0+1
            o1.z = (g2 + g3 + g4) * inv3;   // d0+2
            o1.w = (g3 + g4 + g5) * inv3;   // d0+3
            o2.x = (g4 + g5 + g6) * inv3;   // d0+4
            o2.y = (g5 + g6 + g7) * inv3;   // d0+5
            o2.z = (g6 + g7 + g8) * inv3;   // d0+6
            o2.w = (g7 + g8 + g9) * inv3;   // d0+7
            size_t orow = (size_t)((i0 + row) * 16 + l16);
            *reinterpret_cast<float4*>(&out[orow * 512 + d0]) = o1;
            *reinterpret_cast<float4*>(&out[orow * 512 + d0 + 4]) = o2;
        }
    }
}

extern "C" void kernel_launch(void* const* d_in, const int* in_sizes, int n_in,
                              void* d_out, int out_size, void* d_ws, size_t ws_size,
                              hipStream_t stream)
{
    const float* x  = (const float*)d_in[0];   // 8*32*512
    const float* W1 = (const float*)d_in[1];   // 16*512
    const float* b1 = (const float*)d_in[2];   // 512
    const float* W2 = (const float*)d_in[3];   // 512*8192
    const float* b2 = (const float*)d_in[4];   // 8192
    float* out = (float*)d_out;                // 8192*16*512 fp32

    char* ws = (char*)d_ws;
    ushort_t* h    = (ushort_t*)(ws);                         // 8 MiB
    ushort_t* W2T  = (ushort_t*)(ws + (size_t)(8u << 20));    // 8 MiB
    float*    rden = (float*)(ws + (size_t)(16u << 20));      // 256 KiB
    // P (2 MiB) lives at the head of d_out: only needed until k_rdenom,
    // and k2_final overwrites all of out afterwards (stream-ordered).
    float*    P    = (float*)d_out;

    k_prep<<<dim3(256, 16), 256, 0, stream>>>(W2, W2T);
    k1_hidden<<<8192, 256, 0, stream>>>(x, W1, b1, h);
    k2_sums<<<dim3(64, 64), 256, 0, stream>>>(h, W2T, b2, P);
    k_rdenom<<<256, 256, 0, stream>>>(P, rden);
    k2_final<<<dim3(64, 64), 256, 0, stream>>>(h, W2T, b2, x, rden, out);
}

// Round 5
// 584.919 us; speedup vs baseline: 1.0214x; 1.0214x over previous
//
#include <hip/hip_runtime.h>
#include <stdint.h>

typedef __attribute__((ext_vector_type(8))) short short8;
typedef __attribute__((ext_vector_type(4))) float floatx4;
typedef unsigned short ushort_t;

__device__ __forceinline__ ushort_t f2bf(float f) {
    union { float f; unsigned int i; } v; v.f = f;
    unsigned int r = v.i + 0x7fffu + ((v.i >> 16) & 1u);  // RNE
    return (ushort_t)(r >> 16);
}

// B=8, N=1024 (rows R=8192), P=16, D=512 (GEMM K), E=8192 (P*D)

// ---------- W2 fp32 [512][8192] -> W2T bf16 [8192][512] ----------
__global__ __launch_bounds__(256) void k_prep(
    const float* __restrict__ W2, ushort_t* __restrict__ W2T)
{
    __shared__ float t[32][33];
    const int tid = threadIdx.x;
    const int tx = tid & 31, ty = tid >> 5;      // 32 x 8
    const int e0 = blockIdx.x * 32, k0 = blockIdx.y * 32;
#pragma unroll
    for (int i = 0; i < 4; ++i)
        t[ty + i * 8][tx] = W2[(size_t)(k0 + ty + i * 8) * 8192 + e0 + tx];
    __syncthreads();
#pragma unroll
    for (int i = 0; i < 4; ++i)
        W2T[(size_t)(e0 + ty + i * 8) * 512 + k0 + tx] = f2bf(t[tx][ty + i * 8]);
}

// ---------- h[r][d] = relu(xp[r][:16] @ W1[:, d] + b1[d]), bf16 out ----------
__global__ __launch_bounds__(256) void k1_hidden(
    const float* __restrict__ x, const float* __restrict__ W1,
    const float* __restrict__ b1, ushort_t* __restrict__ h)
{
    __shared__ float xs[16];
    const int r = blockIdx.x;
    const int tid = threadIdx.x;
    if (tid < 16) xs[tid] = x[r * 16 + tid];
    __syncthreads();
#pragma unroll
    for (int dd = 0; dd < 2; ++dd) {
        int d = tid + dd * 256;
        float s = b1[d];
#pragma unroll
        for (int p = 0; p < 16; ++p)
            s += xs[p] * W1[p * 512 + d];
        s = s > 0.f ? s : 0.f;
        h[(size_t)r * 512 + d] = f2bf(s);
    }
}

// ---------- pass A: pipelined GEMM -> exp column partial sums ----------
// 128x128 tile, BK=32, double-buffered LDS, register prefetch one K-step ahead.
__global__ __launch_bounds__(256) void k2_sums(
    const ushort_t* __restrict__ h,     // [8192][512] bf16
    const ushort_t* __restrict__ W2T,   // [8192][512] bf16
    const float* __restrict__ b2,       // [8192]
    float* __restrict__ P)              // [64 row-blocks][8192] partial col sums
{
    __shared__ __align__(16) ushort_t As[2][128 * 32];
    __shared__ __align__(16) ushort_t Bs[2][128 * 32];
    __shared__ float csum[128];
    const int tid = threadIdx.x;
    const int lane = tid & 63;
    const int wave = tid >> 6;
    const int quad = lane >> 4;
    const int l16 = lane & 15;
    const int i0 = blockIdx.x * 128;
    const int e0 = blockIdx.y * 128;
    const int wr = (wave >> 1) * 64;
    const int wc = (wave & 1) * 64;

    if (tid < 128) csum[tid] = 0.f;

    // staging geometry (two 16B chunks per thread per matrix)
    const int q0 = tid, q1 = tid + 256;
    const int row0 = q0 >> 2, c0 = q0 & 3;
    const int row1 = q1 >> 2, c1 = q1 & 3;
    const int w0 = row0 * 32 + ((c0 ^ (row0 & 3)) << 3);
    const int w1 = row1 * 32 + ((c1 ^ (row1 & 3)) << 3);
    const ushort_t* gA0 = &h[(size_t)(i0 + row0) * 512 + c0 * 8];
    const ushort_t* gA1 = &h[(size_t)(i0 + row1) * 512 + c1 * 8];
    const ushort_t* gB0 = &W2T[(size_t)(e0 + row0) * 512 + c0 * 8];
    const ushort_t* gB1 = &W2T[(size_t)(e0 + row1) * 512 + c1 * 8];

    floatx4 acc[4][4];
#pragma unroll
    for (int i = 0; i < 4; ++i)
#pragma unroll
        for (int j = 0; j < 4; ++j)
            acc[i][j] = (floatx4){0.f, 0.f, 0.f, 0.f};

    // prologue: stage K-step 0
    uint4 a0 = *reinterpret_cast<const uint4*>(gA0);
    uint4 a1 = *reinterpret_cast<const uint4*>(gA1);
    uint4 b0 = *reinterpret_cast<const uint4*>(gB0);
    uint4 b1 = *reinterpret_cast<const uint4*>(gB1);
    *reinterpret_cast<uint4*>(&As[0][w0]) = a0;
    *reinterpret_cast<uint4*>(&As[0][w1]) = a1;
    *reinterpret_cast<uint4*>(&Bs[0][w0]) = b0;
    *reinterpret_cast<uint4*>(&Bs[0][w1]) = b1;
    __syncthreads();

    int cur = 0;
    for (int kt = 0; kt < 16; ++kt) {
        uint4 na0, na1, nb0, nb1;
        if (kt < 15) {                         // issue next-step loads (latency hidden below)
            int k0 = (kt + 1) * 32;
            na0 = *reinterpret_cast<const uint4*>(gA0 + k0);
            na1 = *reinterpret_cast<const uint4*>(gA1 + k0);
            nb0 = *reinterpret_cast<const uint4*>(gB0 + k0);
            nb1 = *reinterpret_cast<const uint4*>(gB1 + k0);
        }
        short8 af[4], bfr[4];
#pragma unroll
        for (int i = 0; i < 4; ++i) {
            int m = wr + i * 16 + l16;
            af[i] = *reinterpret_cast<const short8*>(&As[cur][m * 32 + ((quad ^ (m & 3)) << 3)]);
            int n = wc + i * 16 + l16;
            bfr[i] = *reinterpret_cast<const short8*>(&Bs[cur][n * 32 + ((quad ^ (n & 3)) << 3)]);
        }
#pragma unroll
        for (int i = 0; i < 4; ++i)
#pragma unroll
            for (int j = 0; j < 4; ++j)
                acc[i][j] = __builtin_amdgcn_mfma_f32_16x16x32_bf16(af[i], bfr[j], acc[i][j], 0, 0, 0);
        if (kt < 15) {                         // vmcnt wait lands here, after the MFMAs
            *reinterpret_cast<uint4*>(&As[cur ^ 1][w0]) = na0;
            *reinterpret_cast<uint4*>(&As[cur ^ 1][w1]) = na1;
            *reinterpret_cast<uint4*>(&Bs[cur ^ 1][w0]) = nb0;
            *reinterpret_cast<uint4*>(&Bs[cur ^ 1][w1]) = nb1;
        }
        __syncthreads();
        cur ^= 1;
    }

#pragma unroll
    for (int j = 0; j < 4; ++j) {
        int eg = e0 + wc + j * 16 + l16;
        float b2v = b2[eg];
        float csj = 0.f;
#pragma unroll
        for (int i = 0; i < 4; ++i)
#pragma unroll
            for (int r = 0; r < 4; ++r) {
                float v = acc[i][j][r] + b2v;
                v = v > 0.f ? v : 0.f;
                csj += __expf(v);
            }
        csj += __shfl_xor(csj, 16, 64);
        csj += __shfl_xor(csj, 32, 64);
        if (lane < 16) atomicAdd(&csum[wc + j * 16 + l16], csj);
    }
    __syncthreads();
    if (tid < 128) P[(size_t)blockIdx.x * 8192 + e0 + tid] = csum[tid];
}

// ---------- reduce 8 row-block partials per batch -> reciprocal denominators ----------
__global__ __launch_bounds__(256) void k_rdenom(const float* __restrict__ P,
                                                float* __restrict__ rden)
{
    int idx = blockIdx.x * 256 + threadIdx.x;   // b*8192 + e
    int b = idx >> 13;
    int e = idx & 8191;
    float s = 0.f;
#pragma unroll
    for (int j = 0; j < 8; ++j) s += P[(size_t)(b * 8 + j) * 8192 + e];
    rden[idx] = 1.0f / s;
}

// ---------- pass B: pipelined recompute GEMM with 1-d halo; wave owns 32 rows x 160 e-cols ----------
__global__ __launch_bounds__(256) void k2_final(
    const ushort_t* __restrict__ h,
    const ushort_t* __restrict__ W2T,
    const float* __restrict__ b2,
    const float* __restrict__ x,        // xp [8192][16]
    const float* __restrict__ rden,     // [8][8192]
    float* __restrict__ out)            // [8192*16][512]
{
    __shared__ __align__(16) ushort_t As[2][128 * 32];
    __shared__ __align__(16) ushort_t Bs[2][160 * 32];
    const int tid = threadIdx.x;
    const int lane = tid & 63;
    const int wave = tid >> 6;
    const int quad = lane >> 4;
    const int l16 = lane & 15;
    const int i0 = blockIdx.x * 128;
    const int d0 = blockIdx.y * 8;
    const int ebase = blockIdx.y * 128 - 16;  // e_global of e_local 0 (may be -16)
    const int wrow = wave * 32;               // wave's 32-row slice
    const int b = i0 >> 10;

    // staging geometry: A = 2 chunks/thread, B = 640 chunks (3rd active for tid<128)
    const int q0 = tid, q1 = tid + 256, q2 = tid + 512;
    const int row0 = q0 >> 2, c0 = q0 & 3;
    const int row1 = q1 >> 2, c1 = q1 & 3;
    const int row2 = q2 >> 2, c2 = q2 & 3;
    const bool act2 = q2 < 640;
    const int w0 = row0 * 32 + ((c0 ^ (row0 & 3)) << 3);
    const int w1 = row1 * 32 + ((c1 ^ (row1 & 3)) << 3);
    const int w2 = row2 * 32 + ((c2 ^ (row2 & 3)) << 3);
    int ebr0 = ebase + row0; ebr0 = ebr0 < 0 ? 0 : (ebr0 > 8191 ? 8191 : ebr0);
    int ebr1 = ebase + row1; ebr1 = ebr1 < 0 ? 0 : (ebr1 > 8191 ? 8191 : ebr1);
    int ebr2 = ebase + row2; ebr2 = ebr2 < 0 ? 0 : (ebr2 > 8191 ? 8191 : ebr2);
    const ushort_t* gA0 = &h[(size_t)(i0 + row0) * 512 + c0 * 8];
    const ushort_t* gA1 = &h[(size_t)(i0 + row1) * 512 + c1 * 8];
    const ushort_t* gB0 = &W2T[(size_t)ebr0 * 512 + c0 * 8];
    const ushort_t* gB1 = &W2T[(size_t)ebr1 * 512 + c1 * 8];
    const ushort_t* gB2 = &W2T[(size_t)ebr2 * 512 + c2 * 8];

    floatx4 acc[2][10];
#pragma unroll
    for (int i = 0; i < 2; ++i)
#pragma unroll
        for (int t = 0; t < 10; ++t)
            acc[i][t] = (floatx4){0.f, 0.f, 0.f, 0.f};

    // prologue: stage K-step 0
    {
        uint4 a0 = *reinterpret_cast<const uint4*>(gA0);
        uint4 a1 = *reinterpret_cast<const uint4*>(gA1);
        uint4 b0 = *reinterpret_cast<const uint4*>(gB0);
        uint4 b1 = *reinterpret_cast<const uint4*>(gB1);
        *reinterpret_cast<uint4*>(&As[0][w0]) = a0;
        *reinterpret_cast<uint4*>(&As[0][w1]) = a1;
        *reinterpret_cast<uint4*>(&Bs[0][w0]) = b0;
        *reinterpret_cast<uint4*>(&Bs[0][w1]) = b1;
        if (act2) {
            uint4 b2c = *reinterpret_cast<const uint4*>(gB2);
            *reinterpret_cast<uint4*>(&Bs[0][w2]) = b2c;
        }
    }
    __syncthreads();

    int cur = 0;
    for (int kt = 0; kt < 16; ++kt) {
        uint4 na0, na1, nb0, nb1, nb2;
        if (kt < 15) {
            int k0 = (kt + 1) * 32;
            na0 = *reinterpret_cast<const uint4*>(gA0 + k0);
            na1 = *reinterpret_cast<const uint4*>(gA1 + k0);
            nb0 = *reinterpret_cast<const uint4*>(gB0 + k0);
            nb1 = *reinterpret_cast<const uint4*>(gB1 + k0);
            if (act2) nb2 = *reinterpret_cast<const uint4*>(gB2 + k0);
        }
        short8 af[2], bfr[10];
#pragma unroll
        for (int i = 0; i < 2; ++i) {
            int m = wrow + i * 16 + l16;
            af[i] = *reinterpret_cast<const short8*>(&As[cur][m * 32 + ((quad ^ (m & 3)) << 3)]);
        }
#pragma unroll
        for (int t = 0; t < 10; ++t) {
            int n = t * 16 + l16;
            bfr[t] = *reinterpret_cast<const short8*>(&Bs[cur][n * 32 + ((quad ^ (n & 3)) << 3)]);
        }
#pragma unroll
        for (int i = 0; i < 2; ++i)
#pragma unroll
            for (int t = 0; t < 10; ++t)
                acc[i][t] = __builtin_amdgcn_mfma_f32_16x16x32_bf16(af[i], bfr[t], acc[i][t], 0, 0, 0);
        if (kt < 15) {
            *reinterpret_cast<uint4*>(&As[cur ^ 1][w0]) = na0;
            *reinterpret_cast<uint4*>(&As[cur ^ 1][w1]) = na1;
            *reinterpret_cast<uint4*>(&Bs[cur ^ 1][w0]) = nb0;
            *reinterpret_cast<uint4*>(&Bs[cur ^ 1][w1]) = nb1;
            if (act2) *reinterpret_cast<uint4*>(&Bs[cur ^ 1][w2]) = nb2;
        }
        __syncthreads();
        cur ^= 1;
    }

    // xp values for this thread's 8 rows (global; x is L2-hot, kills LDS conflicts)
    float xv[8];
#pragma unroll
    for (int i = 0; i < 2; ++i)
#pragma unroll
        for (int r = 0; r < 4; ++r)
            xv[i * 4 + r] = x[(size_t)(i0 + wrow + i * 16 + quad * 4 + r) * 16 + l16];

    // acc <- g = exp(relu(acc + b2)) * rden[e] * xp[row][p]   (halo out-of-range -> 0)
#pragma unroll
    for (int t = 0; t < 10; ++t) {
        int el = t * 16 + l16;
        int eg = ebase + el;
        int valid = (eg >= 0) & (eg < 8192);
        int egc = valid ? eg : 0;
        float b2v = b2[egc];
        float scale = valid ? rden[b * 8192 + egc] : 0.f;
#pragma unroll
        for (int i = 0; i < 2; ++i) {
#pragma unroll
            for (int r = 0; r < 4; ++r) {
                float v = acc[i][t][r] + b2v;
                v = v > 0.f ? v : 0.f;
                acc[i][t][r] = __expf(v) * scale * xv[i * 4 + r];
            }
        }
    }

    // in-register 3-tap pool over d; two float4 stores per (i,r)
    const float inv3 = 1.f / 3.f;
#pragma unroll
    for (int i = 0; i < 2; ++i) {
        int rbase = wrow + i * 16 + quad * 4;
#pragma unroll
        for (int r = 0; r < 4; ++r) {
            int row = rbase + r;
            float g0 = acc[i][0][r], g1 = acc[i][1][r], g2 = acc[i][2][r];
            float g3 = acc[i][3][r], g4 = acc[i][4][r], g5 = acc[i][5][r];
            float g6 = acc[i][6][r], g7 = acc[i][7][r], g8 = acc[i][8][r];
            float g9 = acc[i][9][r];
            float4 o1, o2;
            o1.x = (g0 + g1 + g2) * inv3;   // d0+0
            o1.y = (g1 + g2 + g3) * inv3;   // d0+1
            o1.z = (g2 + g3 + g4) * inv3;   // d0+2
            o1.w = (g3 + g4 + g5) * inv3;   // d0+3
            o2.x = (g4 + g5 + g6) * inv3;   // d0+4
            o2.y = (g5 + g6 + g7) * inv3;   // d0+5
            o2.z = (g6 + g7 + g8) * inv3;   // d0+6
            o2.w = (g7 + g8 + g9) * inv3;   // d0+7
            size_t orow = (size_t)((i0 + row) * 16 + l16);
            *reinterpret_cast<float4*>(&out[orow * 512 + d0]) = o1;
            *reinterpret_cast<float4*>(&out[orow * 512 + d0 + 4]) = o2;
        }
    }
}

extern "C" void kernel_launch(void* const* d_in, const int* in_sizes, int n_in,
                              void* d_out, int out_size, void* d_ws, size_t ws_size,
                              hipStream_t stream)
{
    const float* x  = (const float*)d_in[0];   // 8*32*512
    const float* W1 = (const float*)d_in[1];   // 16*512
    const float* b1 = (const float*)d_in[2];   // 512
    const float* W2 = (const float*)d_in[3];   // 512*8192
    const float* b2 = (const float*)d_in[4];   // 8192
    float* out = (float*)d_out;                // 8192*16*512 fp32

    char* ws = (char*)d_ws;
    ushort_t* h    = (ushort_t*)(ws);                         // 8 MiB
    ushort_t* W2T  = (ushort_t*)(ws + (size_t)(8u << 20));    // 8 MiB
    float*    rden = (float*)(ws + (size_t)(16u << 20));      // 256 KiB
    // P (2 MiB) lives at the head of d_out: only needed until k_rdenom,
    // and k2_final overwrites all of out afterwards (stream-ordered).
    float*    P    = (float*)d_out;

    k_prep<<<dim3(256, 16), 256, 0, stream>>>(W2, W2T);
    k1_hidden<<<8192, 256, 0, stream>>>(x, W1, b1, h);
    k2_sums<<<dim3(64, 64), 256, 0, stream>>>(h, W2T, b2, P);
    k_rdenom<<<256, 256, 0, stream>>>(P, rden);
    k2_final<<<dim3(64, 64), 256, 0, stream>>>(h, W2T, b2, x, rden, out);
}